// Round 2
// baseline (127.224 us; speedup 1.0000x reference)
//
#include <hip/hip_runtime.h>
#include <math.h>

#define BATCH 4096
#define NNODES 10000
#define KCAND 100
#define F4_PER_BATCH (NNODES * 2 / 4)   // 5000 float4 per batch row

typedef float f4 __attribute__((ext_vector_type(4)));

// One block (256 threads = 4 waves) per batch:
//   phase 1: gather K=100 candidates, block-wide min/max reduce
//   phase 2: stream-normalize all 10000 points of this batch
__global__ __launch_bounds__(256) void fused_normalize_kernel(
        const float* __restrict__ nodes,
        const int* __restrict__ cand,
        float* __restrict__ out) {
    const int b = blockIdx.x;
    const int tid = threadIdx.x;
    const int wave = tid >> 6;
    const int lane = tid & 63;

    const float* nb = nodes + (size_t)b * (NNODES * 2);

    // ---- phase 1: bbox over valid candidates ----
    float xmin =  INFINITY, xmax = -INFINITY;
    float ymin =  INFINITY, ymax = -INFINITY;
    float any = 0.0f;

    if (tid < KCAND) {
        int id = cand[(size_t)b * KCAND + tid];
        if (id != -1) {
            any = 1.0f;
            const float2 p = *reinterpret_cast<const float2*>(nb + (size_t)id * 2);
            xmin = p.x; xmax = p.x;
            ymin = p.y; ymax = p.y;
        }
    }

    // 64-lane butterfly reduce within each wave
    #pragma unroll
    for (int off = 32; off > 0; off >>= 1) {
        xmin = fminf(xmin, __shfl_xor(xmin, off, 64));
        xmax = fmaxf(xmax, __shfl_xor(xmax, off, 64));
        ymin = fminf(ymin, __shfl_xor(ymin, off, 64));
        ymax = fmaxf(ymax, __shfl_xor(ymax, off, 64));
        any  = fmaxf(any,  __shfl_xor(any,  off, 64));
    }

    // cross-wave combine via LDS (4 waves)
    __shared__ float sxmin[4], sxmax[4], symin[4], symax[4], sany[4];
    if (lane == 0) {
        sxmin[wave] = xmin; sxmax[wave] = xmax;
        symin[wave] = ymin; symax[wave] = ymax;
        sany[wave]  = any;
    }
    __syncthreads();

    // every thread folds the 4 partials (cheap, no second broadcast needed)
    xmin = fminf(fminf(sxmin[0], sxmin[1]), fminf(sxmin[2], sxmin[3]));
    xmax = fmaxf(fmaxf(sxmax[0], sxmax[1]), fmaxf(sxmax[2], sxmax[3]));
    ymin = fminf(fminf(symin[0], symin[1]), fminf(symin[2], symin[3]));
    ymax = fmaxf(fmaxf(symax[0], symax[1]), fmaxf(symax[2], symax[3]));
    any  = fmaxf(fmaxf(sany[0],  sany[1]),  fmaxf(sany[2],  sany[3]));

    const float span = fmaxf(xmax - xmin, ymax - ymin);
    const float r = 1.0f / fmaxf(span, 1e-6f);
    const bool valid = (any != 0.0f);

    // ---- phase 2: stream-normalize this batch row ----
    const f4* src = reinterpret_cast<const f4*>(nb);
    f4* dst = reinterpret_cast<f4*>(out + (size_t)b * (NNODES * 2));

    if (valid) {
        for (int i = tid; i < F4_PER_BATCH; i += 256) {
            f4 v = __builtin_nontemporal_load(src + i);
            v.x = fminf(fmaxf(r * (v.x - xmin), 0.0f), 1.0f);
            v.y = fminf(fmaxf(r * (v.y - ymin), 0.0f), 1.0f);
            v.z = fminf(fmaxf(r * (v.z - xmin), 0.0f), 1.0f);
            v.w = fminf(fmaxf(r * (v.w - ymin), 0.0f), 1.0f);
            __builtin_nontemporal_store(v, dst + i);
        }
    } else {
        for (int i = tid; i < F4_PER_BATCH; i += 256) {
            f4 v = __builtin_nontemporal_load(src + i);
            __builtin_nontemporal_store(v, dst + i);
        }
    }
}

extern "C" void kernel_launch(void* const* d_in, const int* in_sizes, int n_in,
                              void* d_out, int out_size, void* d_ws, size_t ws_size,
                              hipStream_t stream) {
    const float* nodes = (const float*)d_in[0];
    const int* cand = (const int*)d_in[1];
    float* out = (float*)d_out;

    fused_normalize_kernel<<<dim3(BATCH), dim3(256), 0, stream>>>(nodes, cand, out);
}

// Round 3
// 118.194 us; speedup vs baseline: 1.0764x; 1.0764x over previous
//
#include <hip/hip_runtime.h>
#include <math.h>

#define BATCH 4096
#define NNODES 10000
#define KCAND 100
#define F4_PER_BATCH 5000          // 10000 points * 2 floats / 4 per float4
#define NITER 20                   // ceil(5000 / 256)
#define PF 4                       // software-pipeline depth (register tiles)

typedef float f4 __attribute__((ext_vector_type(4)));

// One block (256 threads = 4 waves) per batch.
// Prefetch first PF streaming tiles while the candidate gather chase is in
// flight, reduce bbox, then pipeline the rest (load i+PF before process i).
__global__ __launch_bounds__(256) void fused_normalize_kernel(
        const float* __restrict__ nodes,
        const int* __restrict__ cand,
        float* __restrict__ out) {
    const int b = blockIdx.x;
    const int tid = threadIdx.x;
    const int wave = tid >> 6;
    const int lane = tid & 63;

    const float* nb = nodes + (size_t)b * (NNODES * 2);
    const f4* src = reinterpret_cast<const f4*>(nb);
    f4* dst = reinterpret_cast<f4*>(out + (size_t)b * (NNODES * 2));

    // ---- candidate gather: branchless 2-level chase (cand -> nodes) ----
    const int cidx = tid < KCAND ? tid : (KCAND - 1);
    const int id = cand[(size_t)b * KCAND + cidx];
    const bool valid = (tid < KCAND) && (id != -1);
    const int safe = valid ? id : 0;
    const float2 p = *reinterpret_cast<const float2*>(nb + (size_t)safe * 2);

    // ---- prefetch first PF streaming tiles (independent of gather) ----
    f4 buf[PF];
    #pragma unroll
    for (int j = 0; j < PF; ++j) {
        buf[j] = __builtin_nontemporal_load(src + tid + j * 256);  // < 1024 < 5000
    }

    // ---- bbox reduce ----
    float xmin = valid ? p.x :  INFINITY;
    float xmax = valid ? p.x : -INFINITY;
    float ymin = valid ? p.y :  INFINITY;
    float ymax = valid ? p.y : -INFINITY;
    float any  = valid ? 1.0f : 0.0f;

    #pragma unroll
    for (int off = 32; off > 0; off >>= 1) {
        xmin = fminf(xmin, __shfl_xor(xmin, off, 64));
        xmax = fmaxf(xmax, __shfl_xor(xmax, off, 64));
        ymin = fminf(ymin, __shfl_xor(ymin, off, 64));
        ymax = fmaxf(ymax, __shfl_xor(ymax, off, 64));
        any  = fmaxf(any,  __shfl_xor(any,  off, 64));
    }

    __shared__ float sred[5][4];
    if (lane == 0) {
        sred[0][wave] = xmin; sred[1][wave] = xmax;
        sred[2][wave] = ymin; sred[3][wave] = ymax;
        sred[4][wave] = any;
    }
    __syncthreads();
    xmin = fminf(fminf(sred[0][0], sred[0][1]), fminf(sred[0][2], sred[0][3]));
    xmax = fmaxf(fmaxf(sred[1][0], sred[1][1]), fmaxf(sred[1][2], sred[1][3]));
    ymin = fminf(fminf(sred[2][0], sred[2][1]), fminf(sred[2][2], sred[2][3]));
    ymax = fmaxf(fmaxf(sred[3][0], sred[3][1]), fmaxf(sred[3][2], sred[3][3]));
    any  = fmaxf(fmaxf(sred[4][0], sred[4][1]), fmaxf(sred[4][2], sred[4][3]));

    const float span = fmaxf(xmax - xmin, ymax - ymin);
    const float r = 1.0f / fmaxf(span, 1e-6f);
    const bool ok = (any != 0.0f);
    const float bx = -r * xmin;        // out = clamp(fma(r, v, bx))
    const float by = -r * ymin;

    // ---- pipelined streaming normalize ----
    #pragma unroll
    for (int it = 0; it < NITER; ++it) {
        const int i = tid + it * 256;
        const int ipf = i + PF * 256;
        f4 v = buf[it & (PF - 1)];
        if (ipf < F4_PER_BATCH)
            buf[it & (PF - 1)] = __builtin_nontemporal_load(src + ipf);
        if (i < F4_PER_BATCH) {
            f4 o;
            o.x = fminf(fmaxf(fmaf(r, v.x, bx), 0.0f), 1.0f);
            o.y = fminf(fmaxf(fmaf(r, v.y, by), 0.0f), 1.0f);
            o.z = fminf(fmaxf(fmaf(r, v.z, bx), 0.0f), 1.0f);
            o.w = fminf(fmaxf(fmaf(r, v.w, by), 0.0f), 1.0f);
            if (!ok) o = v;            // no-valid-candidate row: pass through
            __builtin_nontemporal_store(o, dst + i);
        }
    }
}

extern "C" void kernel_launch(void* const* d_in, const int* in_sizes, int n_in,
                              void* d_out, int out_size, void* d_ws, size_t ws_size,
                              hipStream_t stream) {
    const float* nodes = (const float*)d_in[0];
    const int* cand = (const int*)d_in[1];
    float* out = (float*)d_out;

    fused_normalize_kernel<<<dim3(BATCH), dim3(256), 0, stream>>>(nodes, cand, out);
}